// Round 1
// baseline (571.271 us; speedup 1.0000x reference)
//
#include <hip/hip_runtime.h>

#define T_TOK 4096
#define HD 2048
#define NE 8
#define NI 1408

typedef __bf16 bf16x8 __attribute__((ext_vector_type(8)));
typedef float f32x4 __attribute__((ext_vector_type(4)));

__device__ __forceinline__ unsigned short f2bf(float f) {
  unsigned int u = __float_as_uint(f);
  u += 0x7FFFu + ((u >> 16) & 1u);
  return (unsigned short)(u >> 16);
}

__device__ __forceinline__ void gload_lds16(const void* g, void* l) {
  __builtin_amdgcn_global_load_lds(
      (const __attribute__((address_space(1))) unsigned int*)g,
      (__attribute__((address_space(3))) unsigned int*)l, 16, 0, 0);
}

// ---------------- conversions ----------------
__global__ void cvt_x_kernel(const float* __restrict__ src,
                             unsigned short* __restrict__ dst, int n4) {
  int idx = blockIdx.x * blockDim.x + threadIdx.x;
  int stride = gridDim.x * blockDim.x;
  for (int i = idx; i < n4; i += stride) {
    float4 v = ((const float4*)src)[i];
    ushort4 o = { f2bf(v.x), f2bf(v.y), f2bf(v.z), f2bf(v.w) };
    ((ushort4*)dst)[i] = o;
  }
}

// src [E][R][C] f32 -> dst [E][C][R] bf16  (R,C multiples of 32)
__global__ void transpose_cvt_kernel(const float* __restrict__ src,
                                     unsigned short* __restrict__ dst,
                                     int R, int C) {
  __shared__ float tile[32][33];
  int e = blockIdx.z;
  int c0 = blockIdx.x * 32, r0 = blockIdx.y * 32;
  int tx = threadIdx.x, ty = threadIdx.y;
  const float* s = src + (size_t)e * R * C;
  unsigned short* d = dst + (size_t)e * R * C;
#pragma unroll
  for (int j = 0; j < 4; j++) {
    int r = ty + j * 8;
    tile[r][tx] = s[(size_t)(r0 + r) * C + c0 + tx];
  }
  __syncthreads();
#pragma unroll
  for (int j = 0; j < 4; j++) {
    int r = ty + j * 8;
    d[(size_t)(c0 + r) * R + r0 + tx] = f2bf(tile[tx][r]);
  }
}

// ---------------- routing ----------------
__global__ void router_kernel(const float* __restrict__ x,
                              const float* __restrict__ Wr,
                              float* __restrict__ logits,
                              int4* __restrict__ tokinfo,
                              int* __restrict__ cnt) {
  int wv = threadIdx.x >> 6, lane = threadIdx.x & 63;
  int t = blockIdx.x * 4 + wv;
  const float* xr = x + (size_t)t * HD;
  float acc[NE];
#pragma unroll
  for (int e = 0; e < NE; e++) acc[e] = 0.f;
  for (int hi = 0; hi < HD / 64; hi++) {
    int h = hi * 64 + lane;
    float xv = xr[h];
    const float4* w4 = (const float4*)(Wr + (size_t)h * NE);
    float4 a = w4[0], b = w4[1];
    acc[0] += xv * a.x; acc[1] += xv * a.y; acc[2] += xv * a.z; acc[3] += xv * a.w;
    acc[4] += xv * b.x; acc[5] += xv * b.y; acc[6] += xv * b.z; acc[7] += xv * b.w;
  }
#pragma unroll
  for (int m = 32; m > 0; m >>= 1) {
#pragma unroll
    for (int e = 0; e < NE; e++) acc[e] += __shfl_xor(acc[e], m, 64);
  }
  if (lane < NE) logits[(size_t)t * NE + lane] = acc[lane];
  if (lane == 0) {
    int e0 = 0;
#pragma unroll
    for (int e = 1; e < NE; e++) if (acc[e] > acc[e0]) e0 = e;
    int e1 = (e0 == 0) ? 1 : 0;
#pragma unroll
    for (int e = 0; e < NE; e++) if (e != e0 && acc[e] > acc[e1]) e1 = e;
    float ex = expf(acc[e1] - acc[e0]);   // <= 1
    float w0 = 1.f / (1.f + ex);
    float w1 = ex / (1.f + ex);
    atomicAdd(&cnt[e0], 1);
    atomicAdd(&cnt[e1], 1);
    tokinfo[t] = make_int4(e0, e1, __float_as_int(w0), __float_as_int(w1));
  }
}

// cnt[0..7]=counts, cnt[8..15]=offsets, cnt[16..23]=scatter cursors
__global__ void offsets_kernel(int* __restrict__ cnt) {
  int o = 0;
  for (int e = 0; e < NE; e++) { cnt[8 + e] = o; o += cnt[e]; }
}

__global__ void scatter_kernel(const int4* __restrict__ tokinfo,
                               int* __restrict__ cnt,
                               int* __restrict__ row_tok,
                               float* __restrict__ row_w) {
  int t = blockIdx.x * blockDim.x + threadIdx.x;
  if (t >= T_TOK) return;
  int4 info = tokinfo[t];
  int p0 = atomicAdd(&cnt[16 + info.x], 1);
  int r0 = cnt[8 + info.x] + p0;
  row_tok[r0] = t; row_w[r0] = __int_as_float(info.z);
  int p1 = atomicAdd(&cnt[16 + info.y], 1);
  int r1 = cnt[8 + info.y] + p1;
  row_tok[r1] = t; row_w[r1] = __int_as_float(info.w);
}

// ---------------- grouped GEMM 1: act = silu(x@Wg) * (x@Wu) ----------------
// 128x128 tile, BK=32, 4 waves each 64x64 (4x4 frags of 16x16x32 bf16).
// LDS per buffer: A[128][32] + Bg[128][32](N-major) + Bu = 24KB; double buffered.
// XOR swizzle: 16B slot p stores global k-slot p ^ ((row>>1)&3)  -> 2-way banks.
__launch_bounds__(256, 2)
__global__ void gemm1_kernel(const unsigned short* __restrict__ xbf,
                             const unsigned short* __restrict__ Wgt,
                             const unsigned short* __restrict__ Wut,
                             unsigned short* __restrict__ act,
                             const int* __restrict__ row_tok,
                             const int* __restrict__ cnt) {
  const int e = blockIdx.z, mt = blockIdx.y, nt = blockIdx.x;
  const int c = cnt[e];
  if (mt * 128 >= c) return;
  const int off = cnt[8 + e];
  const int rowbase = off + mt * 128, rowend = off + c;
  const int i0 = nt * 128;
  __shared__ __align__(16) char smem[49152];
  const int lane = threadIdx.x & 63, w = threadIdx.x >> 6;
  const int wr = w >> 1, wc = w & 1;

  const int rr0 = w * 16 + (lane >> 2);
  const int rr1 = rr0 + 64;
  const int q0 = (lane & 3) ^ ((rr0 >> 1) & 3);
  const int q1 = (lane & 3) ^ ((rr1 >> 1) & 3);
  int g0 = rowbase + rr0; if (g0 > rowend - 1) g0 = rowend - 1;
  int g1 = rowbase + rr1; if (g1 > rowend - 1) g1 = rowend - 1;
  const size_t tokA0 = (size_t)row_tok[g0] * HD;
  const size_t tokA1 = (size_t)row_tok[g1] * HD;
  const size_t bB0 = ((size_t)e * NI + i0 + rr0) * HD;
  const size_t bB1 = ((size_t)e * NI + i0 + rr1) * HD;
  const int ldsA = w * 1024;

  f32x4 zero = {0.f, 0.f, 0.f, 0.f};
  f32x4 accg[4][4], accu[4][4];
#pragma unroll
  for (int a = 0; a < 4; a++)
#pragma unroll
    for (int b = 0; b < 4; b++) { accg[a][b] = zero; accu[a][b] = zero; }

  auto stage = [&](int buf, int ks) {
    const int k0 = ks * 32;
    char* base = smem + buf * 24576;
    gload_lds16(xbf + tokA0 + k0 + q0 * 8, base + ldsA);
    gload_lds16(xbf + tokA1 + k0 + q1 * 8, base + ldsA + 4096);
    gload_lds16(Wgt + bB0 + k0 + q0 * 8, base + 8192 + ldsA);
    gload_lds16(Wgt + bB1 + k0 + q1 * 8, base + 8192 + ldsA + 4096);
    gload_lds16(Wut + bB0 + k0 + q0 * 8, base + 16384 + ldsA);
    gload_lds16(Wut + bB1 + k0 + q1 * 8, base + 16384 + ldsA + 4096);
  };
  stage(0, 0);
  const int rl = lane & 15, kslot = lane >> 4;
  for (int ks = 0; ks < HD / 32; ks++) {
    const int buf = ks & 1;
    if (ks + 1 < HD / 32) stage(buf ^ 1, ks + 1);
    __syncthreads();
    const char* base = smem + buf * 24576;
    bf16x8 af[4], bg[4], bu[4];
#pragma unroll
    for (int mi = 0; mi < 4; mi++) {
      int r = wr * 64 + mi * 16 + rl;
      int byt = r * 64 + ((kslot ^ ((r >> 1) & 3)) << 4);
      af[mi] = *(const bf16x8*)(base + byt);
    }
#pragma unroll
    for (int ni = 0; ni < 4; ni++) {
      int r = wc * 64 + ni * 16 + rl;
      int byt = r * 64 + ((kslot ^ ((r >> 1) & 3)) << 4);
      bg[ni] = *(const bf16x8*)(base + 8192 + byt);
      bu[ni] = *(const bf16x8*)(base + 16384 + byt);
    }
#pragma unroll
    for (int mi = 0; mi < 4; mi++)
#pragma unroll
      for (int ni = 0; ni < 4; ni++) {
        accg[mi][ni] = __builtin_amdgcn_mfma_f32_16x16x32_bf16(af[mi], bg[ni], accg[mi][ni], 0, 0, 0);
        accu[mi][ni] = __builtin_amdgcn_mfma_f32_16x16x32_bf16(af[mi], bu[ni], accu[mi][ni], 0, 0, 0);
      }
    __syncthreads();
  }
  const int rh = lane >> 4;
#pragma unroll
  for (int mi = 0; mi < 4; mi++)
#pragma unroll
    for (int ni = 0; ni < 4; ni++)
#pragma unroll
      for (int j = 0; j < 4; j++) {
        int grow = rowbase + wr * 64 + mi * 16 + rh * 4 + j;
        if (grow < rowend) {
          int gcol = i0 + wc * 64 + ni * 16 + rl;
          float g = accg[mi][ni][j], u = accu[mi][ni][j];
          float val = g / (1.f + __expf(-g)) * u;
          act[(size_t)grow * NI + gcol] = f2bf(val);
        }
      }
}

// ---------------- grouped GEMM 2: out[tok] += w * (act @ Wd) ----------------
__launch_bounds__(256, 2)
__global__ void gemm2_kernel(const unsigned short* __restrict__ act,
                             const unsigned short* __restrict__ Wdt,
                             float* __restrict__ out,
                             const int* __restrict__ row_tok,
                             const float* __restrict__ row_w,
                             const int* __restrict__ cnt) {
  const int e = blockIdx.z, mt = blockIdx.y, nt = blockIdx.x;
  const int c = cnt[e];
  if (mt * 128 >= c) return;
  const int off = cnt[8 + e];
  const int rowbase = off + mt * 128, rowend = off + c;
  const int n0 = nt * 128;
  __shared__ __align__(16) char smem[32768];
  const int lane = threadIdx.x & 63, w = threadIdx.x >> 6;
  const int wr = w >> 1, wc = w & 1;

  const int rr0 = w * 16 + (lane >> 2);
  const int rr1 = rr0 + 64;
  const int q0 = (lane & 3) ^ ((rr0 >> 1) & 3);
  const int q1 = (lane & 3) ^ ((rr1 >> 1) & 3);
  int g0 = rowbase + rr0; if (g0 > rowend - 1) g0 = rowend - 1;
  int g1 = rowbase + rr1; if (g1 > rowend - 1) g1 = rowend - 1;
  const size_t aA0 = (size_t)g0 * NI;
  const size_t aA1 = (size_t)g1 * NI;
  const size_t bB0 = ((size_t)e * HD + n0 + rr0) * NI;
  const size_t bB1 = ((size_t)e * HD + n0 + rr1) * NI;
  const int ldsA = w * 1024;

  f32x4 zero = {0.f, 0.f, 0.f, 0.f};
  f32x4 acc[4][4];
#pragma unroll
  for (int a = 0; a < 4; a++)
#pragma unroll
    for (int b = 0; b < 4; b++) acc[a][b] = zero;

  auto stage = [&](int buf, int ks) {
    const int k0 = ks * 32;
    char* base = smem + buf * 16384;
    gload_lds16(act + aA0 + k0 + q0 * 8, base + ldsA);
    gload_lds16(act + aA1 + k0 + q1 * 8, base + ldsA + 4096);
    gload_lds16(Wdt + bB0 + k0 + q0 * 8, base + 8192 + ldsA);
    gload_lds16(Wdt + bB1 + k0 + q1 * 8, base + 8192 + ldsA + 4096);
  };
  stage(0, 0);
  const int rl = lane & 15, kslot = lane >> 4;
  const int NK = NI / 32;
  for (int ks = 0; ks < NK; ks++) {
    const int buf = ks & 1;
    if (ks + 1 < NK) stage(buf ^ 1, ks + 1);
    __syncthreads();
    const char* base = smem + buf * 16384;
    bf16x8 af[4], bf[4];
#pragma unroll
    for (int mi = 0; mi < 4; mi++) {
      int r = wr * 64 + mi * 16 + rl;
      int byt = r * 64 + ((kslot ^ ((r >> 1) & 3)) << 4);
      af[mi] = *(const bf16x8*)(base + byt);
    }
#pragma unroll
    for (int ni = 0; ni < 4; ni++) {
      int r = wc * 64 + ni * 16 + rl;
      int byt = r * 64 + ((kslot ^ ((r >> 1) & 3)) << 4);
      bf[ni] = *(const bf16x8*)(base + 8192 + byt);
    }
#pragma unroll
    for (int mi = 0; mi < 4; mi++)
#pragma unroll
      for (int ni = 0; ni < 4; ni++)
        acc[mi][ni] = __builtin_amdgcn_mfma_f32_16x16x32_bf16(af[mi], bf[ni], acc[mi][ni], 0, 0, 0);
    __syncthreads();
  }
  const int rh = lane >> 4;
#pragma unroll
  for (int mi = 0; mi < 4; mi++)
#pragma unroll
    for (int ni = 0; ni < 4; ni++)
#pragma unroll
      for (int j = 0; j < 4; j++) {
        int grow = rowbase + wr * 64 + mi * 16 + rh * 4 + j;
        if (grow < rowend) {
          int t = row_tok[grow];
          float wgt = row_w[grow];
          int gcol = n0 + wc * 64 + ni * 16 + rl;
          unsafeAtomicAdd(&out[(size_t)t * HD + gcol], wgt * acc[mi][ni][j]);
        }
      }
}

// ---------------- launch ----------------
extern "C" void kernel_launch(void* const* d_in, const int* in_sizes, int n_in,
                              void* d_out, int out_size, void* d_ws, size_t ws_size,
                              hipStream_t stream) {
  const float* x  = (const float*)d_in[0];
  const float* Wr = (const float*)d_in[1];
  const float* Wg = (const float*)d_in[2];
  const float* Wu = (const float*)d_in[3];
  const float* Wd = (const float*)d_in[4];
  float* out = (float*)d_out;
  char* ws = (char*)d_ws;

  // ws layout (bytes)
  unsigned short* xbf = (unsigned short*)(ws);                 // 16,777,216
  unsigned short* Wgt = (unsigned short*)(ws + 16777216);      // 46,137,344
  unsigned short* Wut = (unsigned short*)(ws + 62914560);      // 46,137,344
  unsigned short* Wdt = (unsigned short*)(ws + 109051904);     // 46,137,344
  unsigned short* act = (unsigned short*)(ws + 155189248);     // 23,068,672
  int4*  tokinfo      = (int4*)(ws + 178257920);               // 65,536
  int*   row_tok      = (int*)(ws + 178323456);                // 32,768
  float* row_w        = (float*)(ws + 178356224);              // 32,768
  int*   cnt          = (int*)(ws + 178388992);                // 96

  hipMemsetAsync(out, 0, (size_t)T_TOK * HD * sizeof(float), stream);
  hipMemsetAsync(cnt, 0, 96, stream);

  cvt_x_kernel<<<2048, 256, 0, stream>>>(x, xbf, T_TOK * HD / 4);
  transpose_cvt_kernel<<<dim3(NI / 32, HD / 32, NE), dim3(32, 8), 0, stream>>>(Wg, Wgt, HD, NI);
  transpose_cvt_kernel<<<dim3(NI / 32, HD / 32, NE), dim3(32, 8), 0, stream>>>(Wu, Wut, HD, NI);
  transpose_cvt_kernel<<<dim3(HD / 32, NI / 32, NE), dim3(32, 8), 0, stream>>>(Wd, Wdt, NI, HD);

  router_kernel<<<T_TOK / 4, 256, 0, stream>>>(x, Wr, out + (size_t)T_TOK * HD, tokinfo, cnt);
  offsets_kernel<<<1, 1, 0, stream>>>(cnt);
  scatter_kernel<<<T_TOK / 256, 256, 0, stream>>>(tokinfo, cnt, row_tok, row_w);

  gemm1_kernel<<<dim3(NI / 128, 32, NE), 256, 0, stream>>>(xbf, Wgt, Wut, act, row_tok, cnt);
  gemm2_kernel<<<dim3(HD / 128, 32, NE), 256, 0, stream>>>(act, Wdt, out, row_tok, row_w, cnt);
}